// Round 3
// baseline (3788.783 us; speedup 1.0000x reference)
//
#include <hip/hip_runtime.h>

// CrossLayerTranscoder. R3:
//  - encoder: R2 reg-staged 128x128 (unchanged) + fused Wd f32->bf16 conversion
//    as 2 extra grid-z slices (overlaps encoder compute).
//  - decoder: deep-pipelined bf16 GEMM. BM=256 BN=128 BK=32, 256 threads
//    (4 waves of 128x64), 3 LDS buffers (72 KB, 2 blocks/CU), global_load_lds
//    staging with pre-swizzled global source (T2), counted vmcnt(6) (T4),
//    raw s_barrier, setprio around MFMA (T5). Heavy-first z gives perfect
//    2-block/CU pairing (7+0, 6+1, 5+2, 4+3).

#define MT 2048   // B*S
#define HD 1024   // H
#define FD 4096   // F
#define LL 8      // L

typedef __attribute__((ext_vector_type(8))) short short8;
typedef __attribute__((ext_vector_type(4))) float f32x4;
typedef __attribute__((ext_vector_type(4))) unsigned short ushort4v;

typedef const __attribute__((address_space(1))) void GV;
typedef __attribute__((address_space(3))) void LV;

__device__ __forceinline__ void gload16(const void* g, void* l) {
  __builtin_amdgcn_global_load_lds((GV*)g, (LV*)l, 16, 0, 0);
}

#define BAR()                                  \
  do {                                         \
    __builtin_amdgcn_sched_barrier(0);         \
    __builtin_amdgcn_s_barrier();              \
    __builtin_amdgcn_sched_barrier(0);         \
  } while (0)

__device__ __forceinline__ unsigned int f2bf1(float x) {
  unsigned u = __float_as_uint(x);
  return (u + 0x7FFFu + ((u >> 16) & 1u)) >> 16;   // RNE f32->bf16
}

// ---- f32 tile staging (128x64, row stride ld), reg-staged (enc/fallback) --
__device__ __forceinline__ void load_tile(const float* __restrict__ base, int ld,
                                          float4* r) {
  const int t = threadIdx.x;
#pragma unroll
  for (int i = 0; i < 8; ++i) {
    int idx = t + 256 * i;
    int row = idx >> 4;
    int c4  = idx & 15;
    r[i] = *(const float4*)(base + (size_t)row * ld + c4 * 4);
  }
}

__device__ __forceinline__ void write_tile(char* lds, const float4* r) {
  const int t = threadIdx.x;
#pragma unroll
  for (int i = 0; i < 8; ++i) {
    int idx = t + 256 * i;
    int row = idx >> 4;
    int c4  = idx & 15;
    int off = (row * 128 + c4 * 8) ^ ((row & 7) << 4);
    unsigned lo = f2bf1(r[i].x) | (f2bf1(r[i].y) << 16);
    unsigned hi = f2bf1(r[i].z) | (f2bf1(r[i].w) << 16);
    *(uint2*)(lds + off) = make_uint2(lo, hi);
  }
}

// ---- bf16 tile staging (128x64) for fallback decoder ----------------------
__device__ __forceinline__ void load_tile_bf(const unsigned short* __restrict__ base,
                                             int ld, short8* r) {
  const int t = threadIdx.x;
#pragma unroll
  for (int i = 0; i < 4; ++i) {
    int idx = t + 256 * i;
    int row = idx >> 3;
    int c8  = idx & 7;
    r[i] = *(const short8*)(base + (size_t)row * ld + c8 * 8);
  }
}

__device__ __forceinline__ void write_tile_bf(char* lds, const short8* r) {
  const int t = threadIdx.x;
#pragma unroll
  for (int i = 0; i < 4; ++i) {
    int idx = t + 256 * i;
    int row = idx >> 3;
    int c8  = idx & 7;
    int off = (row * 128 + c8 * 16) ^ ((row & 7) << 4);
    *(short8*)(lds + off) = r[i];
  }
}

// One BK=64 step (enc/fallback): 2 x (read frags + 16 MFMA).
__device__ __forceinline__ void compute_tile(const char* sA, const char* sB,
                                             f32x4 acc[4][4], int wr, int wc,
                                             int l16, int h16) {
#pragma unroll
  for (int ks = 0; ks < 2; ++ks) {
    short8 a[4], b[4];
#pragma unroll
    for (int i = 0; i < 4; ++i) {
      int row = wr * 64 + i * 16 + l16;
      a[i] = *(const short8*)(sA + ((row * 128 + ks * 64 + h16 * 16) ^ ((row & 7) << 4)));
    }
#pragma unroll
    for (int j = 0; j < 4; ++j) {
      int col = wc * 64 + j * 16 + l16;
      b[j] = *(const short8*)(sB + ((col * 128 + ks * 64 + h16 * 16) ^ ((col & 7) << 4)));
    }
#pragma unroll
    for (int i = 0; i < 4; ++i)
#pragma unroll
      for (int j = 0; j < 4; ++j)
        acc[i][j] = __builtin_amdgcn_mfma_f32_16x16x32_bf16(a[i], b[j], acc[i][j], 0, 0, 0);
  }
}

// ---------------- Encoder (+ fused Wd conversion z-slices) -----------------
__global__ __launch_bounds__(256, 2) void enc_kernel(
    const float* __restrict__ res, const float* __restrict__ We,
    const float* __restrict__ be, const float* __restrict__ thresh,
    float* __restrict__ feats, unsigned short* __restrict__ feats_bf,
    const float* __restrict__ wd_src, unsigned short* __restrict__ wd_dst,
    int conv_z) {
  __shared__ char sA[128 * 64 * 2];
  __shared__ char sB[128 * 64 * 2];

  if ((int)blockIdx.z < conv_z) {
    // Wd f32 -> bf16: 36*HD*FD = 150994944 f32 = 37748736 float4.
    // conv_z=2 slices x 16 x 32 = 1024 chunks x (256 thr x 144 float4).
    size_t chunk = ((size_t)blockIdx.z * 16 + blockIdx.y) * 32 + blockIdx.x;
    size_t base = chunk * 36864 + threadIdx.x;
    const float4* src = (const float4*)wd_src;
#pragma unroll 4
    for (int i = 0; i < 144; ++i) {
      size_t k = base + (size_t)i * 256;
      float4 v = src[k];
      ushort4v o;
      o.x = (unsigned short)f2bf1(v.x);
      o.y = (unsigned short)f2bf1(v.y);
      o.z = (unsigned short)f2bf1(v.z);
      o.w = (unsigned short)f2bf1(v.w);
      *(ushort4v*)(wd_dst + k * 4) = o;
    }
    return;
  }

  const int l  = blockIdx.z - conv_z;
  const int m0 = blockIdx.y * 128;
  const int f0 = blockIdx.x * 128;

  const float* Abase = res + (size_t)l * MT * HD + (size_t)m0 * HD;
  const float* Bbase = We  + (size_t)l * FD * HD + (size_t)f0 * HD;

  const int t = threadIdx.x;
  const int lane = t & 63, wave = t >> 6;
  const int wr = wave >> 1, wc = wave & 1;
  const int l16 = lane & 15, h16 = lane >> 4;

  f32x4 acc[4][4];
#pragma unroll
  for (int i = 0; i < 4; ++i)
#pragma unroll
    for (int j = 0; j < 4; ++j) acc[i][j] = (f32x4){0.f, 0.f, 0.f, 0.f};

  float4 ra[8], rb[8];
  load_tile(Abase, HD, ra);
  load_tile(Bbase, HD, rb);

  const int NK = HD / 64;
  for (int kt = 0; kt < NK; ++kt) {
    write_tile(sA, ra);
    write_tile(sB, rb);
    __syncthreads();
    if (kt + 1 < NK) {
      load_tile(Abase + (kt + 1) * 64, HD, ra);
      load_tile(Bbase + (kt + 1) * 64, HD, rb);
    }
    compute_tile(sA, sB, acc, wr, wc, l16, h16);
    __syncthreads();
  }

  const float th = thresh[l];
#pragma unroll
  for (int j = 0; j < 4; ++j) {
    int col = f0 + wc * 64 + j * 16 + l16;
    float bev = be[(size_t)l * FD + col];
#pragma unroll
    for (int i = 0; i < 4; ++i) {
      int rbase = m0 + wr * 64 + i * 16 + h16 * 4;
#pragma unroll
      for (int q = 0; q < 4; ++q) {
        float v = acc[i][j][q] + bev;
        float g = (v > th) ? v : 0.f;
        size_t idx = ((size_t)l * MT + rbase + q) * FD + col;
        feats[idx] = g;
        if (feats_bf) feats_bf[idx] = (unsigned short)f2bf1(g);
      }
    }
  }
}

// ---------------- Deep-pipelined decoder -----------------------------------
// BM=256 BN=128 BK=32. LDS layout per buffer: A 256 m-rows packed 2/row ->
// 128 phys rows x 128B (16 KB); B 128 h-rows -> 64 x 128B (8 KB).
// Logical (m,k16slot) -> phys (p=m>>1, s=((m&1)<<2)|k), swizzled s^=(p&7).
// gload_lds writes linearly; swizzle applied on the per-lane GLOBAL source.
#define DEC_BUF 24576
__global__ __launch_bounds__(256, 2) void dec_deep(
    const unsigned short* __restrict__ featsbf,
    const unsigned short* __restrict__ wdbf,
    const float* __restrict__ bd, float* __restrict__ recon) {
  __shared__ char lds[3 * DEC_BUF];

  const int lp = 7 - (int)blockIdx.z;   // heavy first; pairs 7+0,6+1,5+2,4+3
  const int m0 = blockIdx.y * 256;
  const int h0 = blockIdx.x * 128;

  const int t = threadIdx.x;
  const int L = t & 63, w = t >> 6;
  const int wm = w >> 1, wn = w & 1;
  const int l16 = L & 15, h16 = L >> 4;

  // staging lane constants: dest slot = L&7 at phys row (chunkbase + L>>3);
  // logical slot there = (L&7) ^ (L>>3)  -> logical m offset + k slot.
  const int sl = (L & 7) ^ (L >> 3);
  const int dm = 2 * (L >> 3) + (sl >> 2);           // m offset in 16-row chunk
  const size_t lane_off = (size_t)dm * FD + (sl & 3) * 8;

  const int NT = (lp + 1) * 128;   // flattened (l, kt32) steps

  f32x4 acc[8][4];
#pragma unroll
  for (int i = 0; i < 8; ++i)
#pragma unroll
    for (int j = 0; j < 4; ++j) acc[i][j] = (f32x4){0.f, 0.f, 0.f, 0.f};

  auto stage = [&](int bi, int tt) {
    const int l = tt >> 7, kt = tt & 127;
    const int p = l * LL - l * (l - 1) / 2 + (lp - l);
    const unsigned short* Ab =
        featsbf + ((size_t)l * MT + m0 + w * 16) * FD + kt * 32 + lane_off;
    const unsigned short* Bb =
        wdbf + ((size_t)p * HD + h0 + w * 16) * FD + kt * 32 + lane_off;
    char* dA = lds + bi * DEC_BUF + w * 1024;
    char* dB = lds + bi * DEC_BUF + 16384 + w * 1024;
#pragma unroll
    for (int c = 0; c < 4; ++c)
      gload16(Ab + (size_t)c * 64 * FD, dA + c * 4096);
#pragma unroll
    for (int c = 0; c < 2; ++c)
      gload16(Bb + (size_t)c * 64 * FD, dB + c * 4096);
  };

  auto compute = [&](int bi) {
    const char* cA = lds + bi * DEC_BUF;
    const char* cB = cA + 16384;
    short8 a[8], b[4];
#pragma unroll
    for (int i = 0; i < 8; ++i) {
      int m = wm * 128 + i * 16 + l16;
      int s = ((m & 1) << 2) | h16;
      a[i] = *(const short8*)(cA + (m >> 1) * 128 + ((s ^ ((m >> 1) & 7)) << 4));
    }
#pragma unroll
    for (int j = 0; j < 4; ++j) {
      int h = wn * 64 + j * 16 + l16;
      int s = ((h & 1) << 2) | h16;
      b[j] = *(const short8*)(cB + (h >> 1) * 128 + ((s ^ ((h >> 1) & 7)) << 4));
    }
    __builtin_amdgcn_s_setprio(1);
#pragma unroll
    for (int i = 0; i < 8; ++i)
#pragma unroll
      for (int j = 0; j < 4; ++j)
        acc[i][j] = __builtin_amdgcn_mfma_f32_16x16x32_bf16(a[i], b[j], acc[i][j], 0, 0, 0);
    __builtin_amdgcn_s_setprio(0);
  };

  // prologue: tiles 0,1 in flight; wait tile 0 (own wave's 6 loads)
  stage(0, 0);
  stage(1, 1);
  asm volatile("s_waitcnt vmcnt(6)" ::: "memory");
  BAR();

  int cur = 0;
  for (int tt = 0; tt < NT; ++tt) {
    if (tt + 2 < NT) {
      int nb = cur + 2;
      if (nb >= 3) nb -= 3;
      stage(nb, tt + 2);          // issue early: loads span the MFMA phase
      compute(cur);
      asm volatile("s_waitcnt vmcnt(6)" ::: "memory");   // tile tt+1 landed
    } else {
      compute(cur);
      asm volatile("s_waitcnt vmcnt(0)" ::: "memory");   // drain tail
    }
    BAR();
    if (++cur == 3) cur = 0;
  }

#pragma unroll
  for (int j = 0; j < 4; ++j) {
    int col = h0 + wn * 64 + j * 16 + l16;
    float bsum = 0.f;
    for (int l = 0; l <= lp; ++l) {
      int p = l * LL - l * (l - 1) / 2 + (lp - l);
      bsum += bd[(size_t)p * HD + col];
    }
#pragma unroll
    for (int i = 0; i < 8; ++i) {
      int rbase = m0 + wm * 128 + i * 16 + h16 * 4;
#pragma unroll
      for (int q = 0; q < 4; ++q)
        recon[((size_t)lp * MT + rbase + q) * HD + col] = acc[i][j][q] + bsum;
    }
  }
}

// ---------------- Fallback decoder (R2 2-phase) ----------------------------
template <bool ABF16>
__global__ __launch_bounds__(256, 2) void dec_kernel(
    const float* __restrict__ feats_f32, const unsigned short* __restrict__ feats_bf,
    const float* __restrict__ Wd, const float* __restrict__ bd,
    float* __restrict__ recon) {
  __shared__ char sA[128 * 64 * 2];
  __shared__ char sB[128 * 64 * 2];

  const int lp = (LL - 1) - (int)blockIdx.z;
  const int m0 = blockIdx.y * 128;
  const int h0 = blockIdx.x * 128;

  const int t = threadIdx.x;
  const int lane = t & 63, wave = t >> 6;
  const int wr = wave >> 1, wc = wave & 1;
  const int l16 = lane & 15, h16 = lane >> 4;

  f32x4 acc[4][4];
#pragma unroll
  for (int i = 0; i < 4; ++i)
#pragma unroll
    for (int j = 0; j < 4; ++j) acc[i][j] = (f32x4){0.f, 0.f, 0.f, 0.f};

  const int nit = (lp + 1) * (FD / 64);

  auto Abf = [&](int it) -> const unsigned short* {
    int l = it >> 6, kt = it & 63;
    return feats_bf + ((size_t)l * MT + m0) * FD + kt * 64;
  };
  auto Af = [&](int it) -> const float* {
    int l = it >> 6, kt = it & 63;
    return feats_f32 + ((size_t)l * MT + m0) * FD + kt * 64;
  };
  auto Bb = [&](int it) -> const float* {
    int l = it >> 6, kt = it & 63;
    int p = l * LL - l * (l - 1) / 2 + (lp - l);
    return Wd + ((size_t)p * HD + h0) * FD + kt * 64;
  };

  short8 rab[4];
  float4 raf[8];
  float4 rb[8];
  if constexpr (ABF16) load_tile_bf(Abf(0), FD, rab); else load_tile(Af(0), FD, raf);
  load_tile(Bb(0), FD, rb);

  for (int it = 0; it < nit; ++it) {
    if constexpr (ABF16) write_tile_bf(sA, rab); else write_tile(sA, raf);
    write_tile(sB, rb);
    __syncthreads();
    if (it + 1 < nit) {
      if constexpr (ABF16) load_tile_bf(Abf(it + 1), FD, rab);
      else                 load_tile(Af(it + 1), FD, raf);
      load_tile(Bb(it + 1), FD, rb);
    }
    compute_tile(sA, sB, acc, wr, wc, l16, h16);
    __syncthreads();
  }

#pragma unroll
  for (int j = 0; j < 4; ++j) {
    int col = h0 + wc * 64 + j * 16 + l16;
    float bsum = 0.f;
    for (int l = 0; l <= lp; ++l) {
      int p = l * LL - l * (l - 1) / 2 + (lp - l);
      bsum += bd[(size_t)p * HD + col];
    }
#pragma unroll
    for (int i = 0; i < 4; ++i) {
      int rbase = m0 + wr * 64 + i * 16 + h16 * 4;
#pragma unroll
      for (int q = 0; q < 4; ++q) {
        recon[((size_t)lp * MT + rbase + q) * HD + col] = acc[i][j][q] + bsum;
      }
    }
  }
}

extern "C" void kernel_launch(void* const* d_in, const int* in_sizes, int n_in,
                              void* d_out, int out_size, void* d_ws, size_t ws_size,
                              hipStream_t stream) {
  const float* res    = (const float*)d_in[0];
  const float* We     = (const float*)d_in[1];
  const float* be     = (const float*)d_in[2];
  const float* Wd     = (const float*)d_in[3];
  const float* bd     = (const float*)d_in[4];
  const float* thresh = (const float*)d_in[5];

  float* recon = (float*)d_out;                       // L*M*H
  float* feats = recon + (size_t)LL * MT * HD;        // L*M*F

  const size_t featsbf_bytes = (size_t)LL * MT * FD * sizeof(unsigned short); // 128 MiB
  const size_t wdbf_bytes    = (size_t)36 * HD * FD * sizeof(unsigned short); // 288 MiB
  const bool use_bf   = ws_size >= featsbf_bytes;
  const bool use_full = ws_size >= featsbf_bytes + wdbf_bytes;

  unsigned short* feats_bf = use_bf ? (unsigned short*)d_ws : nullptr;
  unsigned short* wd_bf    = (unsigned short*)((char*)d_ws + featsbf_bytes);

  dim3 blk(256);
  if (use_full) {
    enc_kernel<<<dim3(FD / 128, MT / 128, LL + 2), blk, 0, stream>>>(
        res, We, be, thresh, feats, feats_bf, Wd, wd_bf, 2);
    dec_deep<<<dim3(HD / 128, MT / 256, LL), blk, 0, stream>>>(
        feats_bf, wd_bf, bd, recon);
  } else {
    enc_kernel<<<dim3(FD / 128, MT / 128, LL), blk, 0, stream>>>(
        res, We, be, thresh, feats, feats_bf, nullptr, nullptr, 0);
    if (use_bf)
      dec_kernel<true><<<dim3(HD / 128, MT / 128, LL), blk, 0, stream>>>(
          feats, feats_bf, Wd, bd, recon);
    else
      dec_kernel<false><<<dim3(HD / 128, MT / 128, LL), blk, 0, stream>>>(
          feats, nullptr, Wd, bd, recon);
  }
}

// Round 5
// 1297.742 us; speedup vs baseline: 2.9195x; 2.9195x over previous
//
#include <hip/hip_runtime.h>

// CrossLayerTranscoder. R5 = R4 with the Wd-conversion sizing bug fixed:
// 4096 enc blocks x 9216 float4 (36/thread) = all 37.75M float4 of Wd.
//  - decoder dec97: m97-structure bf16 GEMM. 128x128 tile, BK=64, 256 thr
//    (4 waves of 64x64, acc[4][4]), global_load_lds staging (16B), double-
//    buffered 64 KB LDS, __syncthreads per K-step. T2 swizzle via
//    pre-swizzled global source slot + XOR'd fragment reads. Each block
//    computes the lp-pair (7-z, z) = constant 9 K-panels -> 512 balanced
//    blocks (2/CU).
//  - encoder: R2 reg-staged 128x128 + Wd f32->bf16 conversion tail.

#define MT 2048   // B*S
#define HD 1024   // H
#define FD 4096   // F
#define LL 8      // L

typedef __attribute__((ext_vector_type(8))) short short8;
typedef __attribute__((ext_vector_type(4))) float f32x4;
typedef __attribute__((ext_vector_type(4))) unsigned short ushort4v;

typedef const __attribute__((address_space(1))) void GV;
typedef __attribute__((address_space(3))) void LV;

__device__ __forceinline__ void gload16(const void* g, void* l) {
  __builtin_amdgcn_global_load_lds((GV*)g, (LV*)l, 16, 0, 0);
}

__device__ __forceinline__ unsigned int f2bf1(float x) {
  unsigned u = __float_as_uint(x);
  return (u + 0x7FFFu + ((u >> 16) & 1u)) >> 16;   // RNE f32->bf16
}

// ---- f32 tile staging (128x64, row stride ld), reg-staged (encoder) -------
__device__ __forceinline__ void load_tile(const float* __restrict__ base, int ld,
                                          float4* r) {
  const int t = threadIdx.x;
#pragma unroll
  for (int i = 0; i < 8; ++i) {
    int idx = t + 256 * i;
    int row = idx >> 4;
    int c4  = idx & 15;
    r[i] = *(const float4*)(base + (size_t)row * ld + c4 * 4);
  }
}

__device__ __forceinline__ void write_tile(char* lds, const float4* r) {
  const int t = threadIdx.x;
#pragma unroll
  for (int i = 0; i < 8; ++i) {
    int idx = t + 256 * i;
    int row = idx >> 4;
    int c4  = idx & 15;
    int off = (row * 128 + c4 * 8) ^ ((row & 7) << 4);
    unsigned lo = f2bf1(r[i].x) | (f2bf1(r[i].y) << 16);
    unsigned hi = f2bf1(r[i].z) | (f2bf1(r[i].w) << 16);
    *(uint2*)(lds + off) = make_uint2(lo, hi);
  }
}

// ---- bf16 tile staging (128x64) for fallback decoder ----------------------
__device__ __forceinline__ void load_tile_bf(const unsigned short* __restrict__ base,
                                             int ld, short8* r) {
  const int t = threadIdx.x;
#pragma unroll
  for (int i = 0; i < 4; ++i) {
    int idx = t + 256 * i;
    int row = idx >> 3;
    int c8  = idx & 7;
    r[i] = *(const short8*)(base + (size_t)row * ld + c8 * 8);
  }
}

__device__ __forceinline__ void write_tile_bf(char* lds, const short8* r) {
  const int t = threadIdx.x;
#pragma unroll
  for (int i = 0; i < 4; ++i) {
    int idx = t + 256 * i;
    int row = idx >> 3;
    int c8  = idx & 7;
    int off = (row * 128 + c8 * 16) ^ ((row & 7) << 4);
    *(short8*)(lds + off) = r[i];
  }
}

// One BK=64 step (enc/fallback): 2 x (read frags + 16 MFMA).
__device__ __forceinline__ void compute_tile(const char* sA, const char* sB,
                                             f32x4 acc[4][4], int wr, int wc,
                                             int l16, int h16) {
#pragma unroll
  for (int ks = 0; ks < 2; ++ks) {
    short8 a[4], b[4];
#pragma unroll
    for (int i = 0; i < 4; ++i) {
      int row = wr * 64 + i * 16 + l16;
      a[i] = *(const short8*)(sA + ((row * 128 + ks * 64 + h16 * 16) ^ ((row & 7) << 4)));
    }
#pragma unroll
    for (int j = 0; j < 4; ++j) {
      int col = wc * 64 + j * 16 + l16;
      b[j] = *(const short8*)(sB + ((col * 128 + ks * 64 + h16 * 16) ^ ((col & 7) << 4)));
    }
#pragma unroll
    for (int i = 0; i < 4; ++i)
#pragma unroll
      for (int j = 0; j < 4; ++j)
        acc[i][j] = __builtin_amdgcn_mfma_f32_16x16x32_bf16(a[i], b[j], acc[i][j], 0, 0, 0);
  }
}

// ---------------- Encoder (+ inline Wd f32->bf16 conversion tail) ----------
__global__ __launch_bounds__(256, 2) void enc_kernel(
    const float* __restrict__ res, const float* __restrict__ We,
    const float* __restrict__ be, const float* __restrict__ thresh,
    float* __restrict__ feats, unsigned short* __restrict__ feats_bf,
    const float* __restrict__ wd_src, unsigned short* __restrict__ wd_dst) {
  __shared__ char sA[128 * 64 * 2];
  __shared__ char sB[128 * 64 * 2];

  const int l  = blockIdx.z;
  const int m0 = blockIdx.y * 128;
  const int f0 = blockIdx.x * 128;

  const float* Abase = res + (size_t)l * MT * HD + (size_t)m0 * HD;
  const float* Bbase = We  + (size_t)l * FD * HD + (size_t)f0 * HD;

  const int t = threadIdx.x;
  const int lane = t & 63, wave = t >> 6;
  const int wr = wave >> 1, wc = wave & 1;
  const int l16 = lane & 15, h16 = lane >> 4;

  f32x4 acc[4][4];
#pragma unroll
  for (int i = 0; i < 4; ++i)
#pragma unroll
    for (int j = 0; j < 4; ++j) acc[i][j] = (f32x4){0.f, 0.f, 0.f, 0.f};

  float4 ra[8], rb[8];
  load_tile(Abase, HD, ra);
  load_tile(Bbase, HD, rb);

  const int NK = HD / 64;
  for (int kt = 0; kt < NK; ++kt) {
    write_tile(sA, ra);
    write_tile(sB, rb);
    __syncthreads();
    if (kt + 1 < NK) {
      load_tile(Abase + (kt + 1) * 64, HD, ra);
      load_tile(Bbase + (kt + 1) * 64, HD, rb);
    }
    compute_tile(sA, sB, acc, wr, wc, l16, h16);
    __syncthreads();
  }

  const float th = thresh[l];
#pragma unroll
  for (int j = 0; j < 4; ++j) {
    int col = f0 + wc * 64 + j * 16 + l16;
    float bev = be[(size_t)l * FD + col];
#pragma unroll
    for (int i = 0; i < 4; ++i) {
      int rbase = m0 + wr * 64 + i * 16 + h16 * 4;
#pragma unroll
      for (int q = 0; q < 4; ++q) {
        float v = acc[i][j][q] + bev;
        float g = (v > th) ? v : 0.f;
        size_t idx = ((size_t)l * MT + rbase + q) * FD + col;
        feats[idx] = g;
        if (feats_bf) feats_bf[idx] = (unsigned short)f2bf1(g);
      }
    }
  }

  // ---- Wd conversion tail: 4096 blocks x 9216 float4 (36/thread) ---------
  // total = 36*HD*FD f32 = 37,748,736 float4.
  if (wd_dst) {
    size_t chunk = ((size_t)blockIdx.z * gridDim.y + blockIdx.y) * gridDim.x
                   + blockIdx.x;                       // 0..4095
    const float4* src = (const float4*)wd_src;
    size_t base = chunk * 9216 + t;
#pragma unroll 4
    for (int i = 0; i < 36; ++i) {
      size_t k = base + (size_t)i * 256;
      float4 v = src[k];
      ushort4v o;
      o.x = (unsigned short)f2bf1(v.x);
      o.y = (unsigned short)f2bf1(v.y);
      o.z = (unsigned short)f2bf1(v.z);
      o.w = (unsigned short)f2bf1(v.w);
      *(ushort4v*)(wd_dst + k * 4) = o;
    }
  }
}

// ---------------- Decoder: m97 structure, gload_lds, paired lp -------------
__global__ __launch_bounds__(256, 2) void dec97(
    const unsigned short* __restrict__ featsbf,
    const unsigned short* __restrict__ wdbf,
    const float* __restrict__ bd, float* __restrict__ recon) {
  __shared__ unsigned short sA[2][128 * 64];   // 2 x 16 KB
  __shared__ unsigned short sB[2][128 * 64];   // 2 x 16 KB

  const int z  = blockIdx.z;            // 0..3 -> lp pair (7-z, z): 9 panels
  const int m0 = blockIdx.y * 128;
  const int h0 = blockIdx.x * 128;

  const int t = threadIdx.x;
  const int L = t & 63, w = t >> 6;
  const int wm = w >> 1, wn = w & 1;
  const int l16 = L & 15, h16 = L >> 4;

  // staging lane constants: instr i of wave w covers LDS rows w*32+i*8..+7,
  // linear dest (HW: base + lane*16). Source slot pre-swizzled so that
  // LDS[row][s'] = global[row][s' ^ (row&7)]  (involution, 128B-coalesced).
  const int rl   = L >> 3;              // row within 8-row group
  const int scol = (L & 7) ^ rl;        // swizzled source 16B-slot
  const int rowb = w * 32 + rl;

  for (int sub = 0; sub < 2; ++sub) {
    const int lp = sub ? z : 7 - z;
    const int NT = (lp + 1) * 64;       // BK=64 tiles over (lp+1) K-panels

    f32x4 acc[4][4];
#pragma unroll
    for (int i = 0; i < 4; ++i)
#pragma unroll
      for (int j = 0; j < 4; ++j) acc[i][j] = (f32x4){0.f, 0.f, 0.f, 0.f};

    auto stage = [&](int buf, int tt) {
      int l = tt >> 6, kt = tt & 63;
      int p = l * LL - l * (l - 1) / 2 + (lp - l);
      const unsigned short* As =
          featsbf + (size_t)(l * MT + m0 + rowb) * FD + kt * 64 + scol * 8;
      const unsigned short* Bs =
          wdbf + (size_t)(p * HD + h0 + rowb) * FD + kt * 64 + scol * 8;
      char* dA = (char*)(&sA[buf][0]) + w * 4096;
      char* dB = (char*)(&sB[buf][0]) + w * 4096;
#pragma unroll
      for (int i = 0; i < 4; ++i) {
        gload16(As + (size_t)i * 8 * FD, dA + i * 1024);
        gload16(Bs + (size_t)i * 8 * FD, dB + i * 1024);
      }
    };

    auto compute = [&](int buf) {
#pragma unroll
      for (int ks = 0; ks < 2; ++ks) {
        short8 a[4], b[4];
#pragma unroll
        for (int i = 0; i < 4; ++i) {
          int row  = wm * 64 + i * 16 + l16;
          int slot = ((ks << 2) | h16) ^ (row & 7);
          a[i] = *(const short8*)((const char*)(&sA[buf][0]) + row * 128 + slot * 16);
        }
#pragma unroll
        for (int j = 0; j < 4; ++j) {
          int col  = wn * 64 + j * 16 + l16;
          int slot = ((ks << 2) | h16) ^ (col & 7);
          b[j] = *(const short8*)((const char*)(&sB[buf][0]) + col * 128 + slot * 16);
        }
#pragma unroll
        for (int i = 0; i < 4; ++i)
#pragma unroll
          for (int j = 0; j < 4; ++j)
            acc[i][j] = __builtin_amdgcn_mfma_f32_16x16x32_bf16(a[i], b[j], acc[i][j], 0, 0, 0);
      }
    };

    stage(0, 0);
    __syncthreads();
    int buf = 0;
    for (int tt = 0; tt < NT; ++tt) {
      if (tt + 1 < NT) stage(buf ^ 1, tt + 1);   // loads span the MFMA phase
      compute(buf);
      __syncthreads();                            // vmcnt(0)+lgkm(0)+barrier
      buf ^= 1;
    }

#pragma unroll
    for (int j = 0; j < 4; ++j) {
      int col = h0 + wn * 64 + j * 16 + l16;
      float bsum = 0.f;
      for (int l = 0; l <= lp; ++l) {
        int p = l * LL - l * (l - 1) / 2 + (lp - l);
        bsum += bd[(size_t)p * HD + col];
      }
#pragma unroll
      for (int i = 0; i < 4; ++i) {
        int rbase = m0 + wm * 64 + i * 16 + h16 * 4;
#pragma unroll
        for (int q = 0; q < 4; ++q)
          recon[((size_t)lp * MT + rbase + q) * HD + col] = acc[i][j][q] + bsum;
      }
    }
  }
}

// ---------------- Fallback decoder (R2 2-phase, reg-staged) ----------------
template <bool ABF16>
__global__ __launch_bounds__(256, 2) void dec_kernel(
    const float* __restrict__ feats_f32, const unsigned short* __restrict__ feats_bf,
    const float* __restrict__ Wd, const float* __restrict__ bd,
    float* __restrict__ recon) {
  __shared__ char sA[128 * 64 * 2];
  __shared__ char sB[128 * 64 * 2];

  const int lp = (LL - 1) - (int)blockIdx.z;
  const int m0 = blockIdx.y * 128;
  const int h0 = blockIdx.x * 128;

  const int t = threadIdx.x;
  const int lane = t & 63, wave = t >> 6;
  const int wr = wave >> 1, wc = wave & 1;
  const int l16 = lane & 15, h16 = lane >> 4;

  f32x4 acc[4][4];
#pragma unroll
  for (int i = 0; i < 4; ++i)
#pragma unroll
    for (int j = 0; j < 4; ++j) acc[i][j] = (f32x4){0.f, 0.f, 0.f, 0.f};

  const int nit = (lp + 1) * (FD / 64);

  auto Abf = [&](int it) -> const unsigned short* {
    int l = it >> 6, kt = it & 63;
    return feats_bf + ((size_t)l * MT + m0) * FD + kt * 64;
  };
  auto Af = [&](int it) -> const float* {
    int l = it >> 6, kt = it & 63;
    return feats_f32 + ((size_t)l * MT + m0) * FD + kt * 64;
  };
  auto Bb = [&](int it) -> const float* {
    int l = it >> 6, kt = it & 63;
    int p = l * LL - l * (l - 1) / 2 + (lp - l);
    return Wd + ((size_t)p * HD + h0) * FD + kt * 64;
  };

  short8 rab[4];
  float4 raf[8];
  float4 rb[8];
  if constexpr (ABF16) load_tile_bf(Abf(0), FD, rab); else load_tile(Af(0), FD, raf);
  load_tile(Bb(0), FD, rb);

  for (int it = 0; it < nit; ++it) {
    if constexpr (ABF16) write_tile_bf(sA, rab); else write_tile(sA, raf);
    write_tile(sB, rb);
    __syncthreads();
    if (it + 1 < nit) {
      if constexpr (ABF16) load_tile_bf(Abf(it + 1), FD, rab);
      else                 load_tile(Af(it + 1), FD, raf);
      load_tile(Bb(it + 1), FD, rb);
    }
    compute_tile(sA, sB, acc, wr, wc, l16, h16);
    __syncthreads();
  }

#pragma unroll
  for (int j = 0; j < 4; ++j) {
    int col = h0 + wc * 64 + j * 16 + l16;
    float bsum = 0.f;
    for (int l = 0; l <= lp; ++l) {
      int p = l * LL - l * (l - 1) / 2 + (lp - l);
      bsum += bd[(size_t)p * HD + col];
    }
#pragma unroll
    for (int i = 0; i < 4; ++i) {
      int rbase = m0 + wr * 64 + i * 16 + h16 * 4;
#pragma unroll
      for (int q = 0; q < 4; ++q) {
        recon[((size_t)lp * MT + rbase + q) * HD + col] = acc[i][j][q] + bsum;
      }
    }
  }
}

extern "C" void kernel_launch(void* const* d_in, const int* in_sizes, int n_in,
                              void* d_out, int out_size, void* d_ws, size_t ws_size,
                              hipStream_t stream) {
  const float* res    = (const float*)d_in[0];
  const float* We     = (const float*)d_in[1];
  const float* be     = (const float*)d_in[2];
  const float* Wd     = (const float*)d_in[3];
  const float* bd     = (const float*)d_in[4];
  const float* thresh = (const float*)d_in[5];

  float* recon = (float*)d_out;                       // L*M*H
  float* feats = recon + (size_t)LL * MT * HD;        // L*M*F

  const size_t featsbf_bytes = (size_t)LL * MT * FD * sizeof(unsigned short); // 128 MiB
  const size_t wdbf_bytes    = (size_t)36 * HD * FD * sizeof(unsigned short); // 288 MiB
  const bool use_bf   = ws_size >= featsbf_bytes;
  const bool use_full = ws_size >= featsbf_bytes + wdbf_bytes;

  unsigned short* feats_bf = use_bf ? (unsigned short*)d_ws : nullptr;
  unsigned short* wd_bf    = (unsigned short*)((char*)d_ws + featsbf_bytes);

  dim3 blk(256);
  if (use_full) {
    enc_kernel<<<dim3(FD / 128, MT / 128, LL), blk, 0, stream>>>(
        res, We, be, thresh, feats, feats_bf, Wd, wd_bf);
    dec97<<<dim3(HD / 128, MT / 128, 4), blk, 0, stream>>>(
        feats_bf, wd_bf, bd, recon);
  } else {
    enc_kernel<<<dim3(FD / 128, MT / 128, LL), blk, 0, stream>>>(
        res, We, be, thresh, feats, feats_bf, nullptr, nullptr);
    if (use_bf)
      dec_kernel<true><<<dim3(HD / 128, MT / 128, LL), blk, 0, stream>>>(
          feats, feats_bf, Wd, bd, recon);
    else
      dec_kernel<false><<<dim3(HD / 128, MT / 128, LL), blk, 0, stream>>>(
          feats, nullptr, Wd, bd, recon);
  }
}

// Round 6
// 1058.505 us; speedup vs baseline: 3.5794x; 1.2260x over previous
//
#include <hip/hip_runtime.h>

// CrossLayerTranscoder. R6:
//  - decoder dec8: deep-pipelined bf16 GEMM (T3+T4+T5). BM=256 BN=128 BK=64,
//    512 thr (8 waves 4Mx2N, per-wave 64x64, acc[4][4]), 3 LDS buffers
//    (144 KB, 1 block/CU), global_load_lds staging with pre-swizzled global
//    source, depth-2 prefetch, counted vmcnt(6) (never 0 mid-loop), raw
//    s_barrier, setprio around 16-MFMA clusters. Paired lp (7-z, z) ->
//    256 blocks = 1/CU, XCD-chunk swizzle.
//  - encoder: R2 reg-staged 128x128 + Wd f32->bf16 conversion tail.

#define MT 2048   // B*S
#define HD 1024   // H
#define FD 4096   // F
#define LL 8      // L

typedef __attribute__((ext_vector_type(8))) short short8;
typedef __attribute__((ext_vector_type(4))) float f32x4;
typedef __attribute__((ext_vector_type(4))) unsigned short ushort4v;

typedef const __attribute__((address_space(1))) void GV;
typedef __attribute__((address_space(3))) void LV;

__device__ __forceinline__ void gload16(const void* g, void* l) {
  __builtin_amdgcn_global_load_lds((GV*)g, (LV*)l, 16, 0, 0);
}

#define BAR()                                  \
  do {                                         \
    __builtin_amdgcn_sched_barrier(0);         \
    __builtin_amdgcn_s_barrier();              \
    __builtin_amdgcn_sched_barrier(0);         \
  } while (0)

__device__ __forceinline__ unsigned int f2bf1(float x) {
  unsigned u = __float_as_uint(x);
  return (u + 0x7FFFu + ((u >> 16) & 1u)) >> 16;   // RNE f32->bf16
}

// ---- f32 tile staging (128x64, row stride ld), reg-staged (encoder) -------
__device__ __forceinline__ void load_tile(const float* __restrict__ base, int ld,
                                          float4* r) {
  const int t = threadIdx.x;
#pragma unroll
  for (int i = 0; i < 8; ++i) {
    int idx = t + 256 * i;
    int row = idx >> 4;
    int c4  = idx & 15;
    r[i] = *(const float4*)(base + (size_t)row * ld + c4 * 4);
  }
}

__device__ __forceinline__ void write_tile(char* lds, const float4* r) {
  const int t = threadIdx.x;
#pragma unroll
  for (int i = 0; i < 8; ++i) {
    int idx = t + 256 * i;
    int row = idx >> 4;
    int c4  = idx & 15;
    int off = (row * 128 + c4 * 8) ^ ((row & 7) << 4);
    unsigned lo = f2bf1(r[i].x) | (f2bf1(r[i].y) << 16);
    unsigned hi = f2bf1(r[i].z) | (f2bf1(r[i].w) << 16);
    *(uint2*)(lds + off) = make_uint2(lo, hi);
  }
}

// ---- bf16 tile staging (128x64) for fallback decoder ----------------------
__device__ __forceinline__ void load_tile_bf(const unsigned short* __restrict__ base,
                                             int ld, short8* r) {
  const int t = threadIdx.x;
#pragma unroll
  for (int i = 0; i < 4; ++i) {
    int idx = t + 256 * i;
    int row = idx >> 3;
    int c8  = idx & 7;
    r[i] = *(const short8*)(base + (size_t)row * ld + c8 * 8);
  }
}

__device__ __forceinline__ void write_tile_bf(char* lds, const short8* r) {
  const int t = threadIdx.x;
#pragma unroll
  for (int i = 0; i < 4; ++i) {
    int idx = t + 256 * i;
    int row = idx >> 3;
    int c8  = idx & 7;
    int off = (row * 128 + c8 * 16) ^ ((row & 7) << 4);
    *(short8*)(lds + off) = r[i];
  }
}

// One BK=64 step (enc/fallback): 2 x (read frags + 16 MFMA).
__device__ __forceinline__ void compute_tile(const char* sA, const char* sB,
                                             f32x4 acc[4][4], int wr, int wc,
                                             int l16, int h16) {
#pragma unroll
  for (int ks = 0; ks < 2; ++ks) {
    short8 a[4], b[4];
#pragma unroll
    for (int i = 0; i < 4; ++i) {
      int row = wr * 64 + i * 16 + l16;
      a[i] = *(const short8*)(sA + ((row * 128 + ks * 64 + h16 * 16) ^ ((row & 7) << 4)));
    }
#pragma unroll
    for (int j = 0; j < 4; ++j) {
      int col = wc * 64 + j * 16 + l16;
      b[j] = *(const short8*)(sB + ((col * 128 + ks * 64 + h16 * 16) ^ ((col & 7) << 4)));
    }
#pragma unroll
    for (int i = 0; i < 4; ++i)
#pragma unroll
      for (int j = 0; j < 4; ++j)
        acc[i][j] = __builtin_amdgcn_mfma_f32_16x16x32_bf16(a[i], b[j], acc[i][j], 0, 0, 0);
  }
}

// ---------------- Encoder (+ inline Wd f32->bf16 conversion tail) ----------
__global__ __launch_bounds__(256, 2) void enc_kernel(
    const float* __restrict__ res, const float* __restrict__ We,
    const float* __restrict__ be, const float* __restrict__ thresh,
    float* __restrict__ feats, unsigned short* __restrict__ feats_bf,
    const float* __restrict__ wd_src, unsigned short* __restrict__ wd_dst) {
  __shared__ char sA[128 * 64 * 2];
  __shared__ char sB[128 * 64 * 2];

  const int l  = blockIdx.z;
  const int m0 = blockIdx.y * 128;
  const int f0 = blockIdx.x * 128;

  const float* Abase = res + (size_t)l * MT * HD + (size_t)m0 * HD;
  const float* Bbase = We  + (size_t)l * FD * HD + (size_t)f0 * HD;

  const int t = threadIdx.x;
  const int lane = t & 63, wave = t >> 6;
  const int wr = wave >> 1, wc = wave & 1;
  const int l16 = lane & 15, h16 = lane >> 4;

  f32x4 acc[4][4];
#pragma unroll
  for (int i = 0; i < 4; ++i)
#pragma unroll
    for (int j = 0; j < 4; ++j) acc[i][j] = (f32x4){0.f, 0.f, 0.f, 0.f};

  float4 ra[8], rb[8];
  load_tile(Abase, HD, ra);
  load_tile(Bbase, HD, rb);

  const int NK = HD / 64;
  for (int kt = 0; kt < NK; ++kt) {
    write_tile(sA, ra);
    write_tile(sB, rb);
    __syncthreads();
    if (kt + 1 < NK) {
      load_tile(Abase + (kt + 1) * 64, HD, ra);
      load_tile(Bbase + (kt + 1) * 64, HD, rb);
    }
    compute_tile(sA, sB, acc, wr, wc, l16, h16);
    __syncthreads();
  }

  const float th = thresh[l];
#pragma unroll
  for (int j = 0; j < 4; ++j) {
    int col = f0 + wc * 64 + j * 16 + l16;
    float bev = be[(size_t)l * FD + col];
#pragma unroll
    for (int i = 0; i < 4; ++i) {
      int rbase = m0 + wr * 64 + i * 16 + h16 * 4;
#pragma unroll
      for (int q = 0; q < 4; ++q) {
        float v = acc[i][j][q] + bev;
        float g = (v > th) ? v : 0.f;
        size_t idx = ((size_t)l * MT + rbase + q) * FD + col;
        feats[idx] = g;
        if (feats_bf) feats_bf[idx] = (unsigned short)f2bf1(g);
      }
    }
  }

  // ---- Wd conversion tail: 4096 blocks x 9216 float4 (36/thread) ---------
  if (wd_dst) {
    size_t chunk = ((size_t)blockIdx.z * gridDim.y + blockIdx.y) * gridDim.x
                   + blockIdx.x;                       // 0..4095
    const float4* src = (const float4*)wd_src;
    size_t base = chunk * 9216 + t;
#pragma unroll 4
    for (int i = 0; i < 36; ++i) {
      size_t k = base + (size_t)i * 256;
      float4 v = src[k];
      ushort4v o;
      o.x = (unsigned short)f2bf1(v.x);
      o.y = (unsigned short)f2bf1(v.y);
      o.z = (unsigned short)f2bf1(v.z);
      o.w = (unsigned short)f2bf1(v.w);
      *(ushort4v*)(wd_dst + k * 4) = o;
    }
  }
}

// ---------------- Decoder: deep pipeline (T3+T4+T5) ------------------------
// LDS per buffer: A 256x64 bf16 (32 KB) + B 128x64 bf16 (16 KB) = 48 KB.
// 3 buffers, depth-2 prefetch. LDS[row][s] = G[row][s ^ (row&7)] via
// pre-swizzled global source slot (linear gload_lds dest).
#define DEC_ABUF 32768
#define DEC_BUFSZ 49152
__global__ __launch_bounds__(512, 2) void dec8(
    const unsigned short* __restrict__ featsbf,
    const unsigned short* __restrict__ wdbf,
    const float* __restrict__ bd, float* __restrict__ recon) {
  __shared__ char lds[3 * DEC_BUFSZ];   // 144 KB -> 1 block/CU

  // XCD-chunk swizzle over 256 blocks (8 XCDs x 32-block chunks, bijective).
  const int flat = (int)(blockIdx.x + 8 * blockIdx.y + 64 * blockIdx.z);
  const int nf = (flat & 7) * 32 + (flat >> 3);
  const int bx = nf & 7;          // h-tile
  const int by = (nf >> 3) & 7;   // m-tile
  const int z  = nf >> 6;         // 0..3 -> lp pair (7-z, z)

  const int m0 = by * 256;
  const int h0 = bx * 128;

  const int t = threadIdx.x;          // 0..511
  const int L = t & 63;
  const int w = t >> 6;               // 8 waves
  const int wm = w >> 1, wn = w & 1;  // 4M x 2N
  const int l16 = L & 15, h16 = L >> 4;

  // staging lane constants: instr i covers rows i*64 + (t>>3); dest slot t&7.
  const int rl   = (t >> 3) & 7;
  const int scol = (t & 7) ^ rl;            // pre-swizzled source 16B-slot
  const int rowl = t >> 3;                  // 0..63
  const size_t laneA = (size_t)(m0 + rowl) * FD + scol * 8;
  const size_t laneB = (size_t)(h0 + rowl) * FD + scol * 8;

  // fragment-read lane constant: slot(ks) = s0 ^ (ks<<2)
  const int s0 = h16 ^ (l16 & 7);

  for (int sub = 0; sub < 2; ++sub) {
    const int lp = sub ? z : 7 - z;
    const int NT = (lp + 1) * 64;     // BK=64 steps over (lp+1) K-panels

    f32x4 acc[4][4];
#pragma unroll
    for (int i = 0; i < 4; ++i)
#pragma unroll
      for (int j = 0; j < 4; ++j) acc[i][j] = (f32x4){0.f, 0.f, 0.f, 0.f};

    auto stage = [&](int bi, int tt) {
      int l = tt >> 6, kt = tt & 63;
      int p = l * LL - ((l * (l - 1)) >> 1) + (lp - l);
      const unsigned short* Ab = featsbf + (size_t)l * MT * FD + kt * 64 + laneA;
      const unsigned short* Bb = wdbf + (size_t)p * HD * FD + kt * 64 + laneB;
      char* dA = lds + bi * DEC_BUFSZ + t * 16;
      char* dB = dA + DEC_ABUF;
#pragma unroll
      for (int i = 0; i < 4; ++i)
        gload16(Ab + (size_t)i * 64 * FD, dA + i * 8192);
#pragma unroll
      for (int i = 0; i < 2; ++i)
        gload16(Bb + (size_t)i * 64 * FD, dB + i * 8192);
    };

    auto compute = [&](int bi) {
      const char* cA = lds + bi * DEC_BUFSZ;
      const char* cB = cA + DEC_ABUF;
#pragma unroll
      for (int ks = 0; ks < 2; ++ks) {
        const int sl = (s0 ^ (ks << 2)) << 4;
        short8 a[4], b[4];
#pragma unroll
        for (int i = 0; i < 4; ++i) {
          int row = wm * 64 + i * 16 + l16;
          a[i] = *(const short8*)(cA + row * 128 + sl);
        }
#pragma unroll
        for (int j = 0; j < 4; ++j) {
          int col = wn * 64 + j * 16 + l16;
          b[j] = *(const short8*)(cB + col * 128 + sl);
        }
        __builtin_amdgcn_s_setprio(1);
#pragma unroll
        for (int i = 0; i < 4; ++i)
#pragma unroll
          for (int j = 0; j < 4; ++j)
            acc[i][j] = __builtin_amdgcn_mfma_f32_16x16x32_bf16(a[i], b[j], acc[i][j], 0, 0, 0);
        __builtin_amdgcn_s_setprio(0);
      }
    };

    // prologue: tiles 0,1 in flight (12 loads); wait tile 0 (6 remain)
    stage(0, 0);
    stage(1, 1);
    asm volatile("s_waitcnt vmcnt(6)" ::: "memory");
    BAR();

    int rd = 0;
    for (int tt = 0; tt < NT; ++tt) {
      int st = rd + 2;
      if (st >= 3) st -= 3;
      if (tt + 2 < NT) stage(st, tt + 2);   // issue early: spans MFMA phase
      compute(rd);
      if (tt + 2 < NT) {
        asm volatile("s_waitcnt vmcnt(6)" ::: "memory");   // tile tt+1 landed
      } else if (tt + 1 < NT) {
        asm volatile("s_waitcnt vmcnt(0)" ::: "memory");   // drain tail
      }
      BAR();
      if (++rd == 3) rd = 0;
    }

#pragma unroll
    for (int j = 0; j < 4; ++j) {
      int col = h0 + wn * 64 + j * 16 + l16;
      float bsum = 0.f;
      for (int l = 0; l <= lp; ++l) {
        int p = l * LL - ((l * (l - 1)) >> 1) + (lp - l);
        bsum += bd[(size_t)p * HD + col];
      }
#pragma unroll
      for (int i = 0; i < 4; ++i) {
        int rbase = m0 + wm * 64 + i * 16 + h16 * 4;
#pragma unroll
        for (int q = 0; q < 4; ++q)
          recon[((size_t)lp * MT + rbase + q) * HD + col] = acc[i][j][q] + bsum;
      }
    }
  }
}

// ---------------- Fallback decoder (R2 2-phase, reg-staged) ----------------
template <bool ABF16>
__global__ __launch_bounds__(256, 2) void dec_kernel(
    const float* __restrict__ feats_f32, const unsigned short* __restrict__ feats_bf,
    const float* __restrict__ Wd, const float* __restrict__ bd,
    float* __restrict__ recon) {
  __shared__ char sA[128 * 64 * 2];
  __shared__ char sB[128 * 64 * 2];

  const int lp = (LL - 1) - (int)blockIdx.z;
  const int m0 = blockIdx.y * 128;
  const int h0 = blockIdx.x * 128;

  const int t = threadIdx.x;
  const int lane = t & 63, wave = t >> 6;
  const int wr = wave >> 1, wc = wave & 1;
  const int l16 = lane & 15, h16 = lane >> 4;

  f32x4 acc[4][4];
#pragma unroll
  for (int i = 0; i < 4; ++i)
#pragma unroll
    for (int j = 0; j < 4; ++j) acc[i][j] = (f32x4){0.f, 0.f, 0.f, 0.f};

  const int nit = (lp + 1) * (FD / 64);

  auto Abf = [&](int it) -> const unsigned short* {
    int l = it >> 6, kt = it & 63;
    return feats_bf + ((size_t)l * MT + m0) * FD + kt * 64;
  };
  auto Af = [&](int it) -> const float* {
    int l = it >> 6, kt = it & 63;
    return feats_f32 + ((size_t)l * MT + m0) * FD + kt * 64;
  };
  auto Bb = [&](int it) -> const float* {
    int l = it >> 6, kt = it & 63;
    int p = l * LL - l * (l - 1) / 2 + (lp - l);
    return Wd + ((size_t)p * HD + h0) * FD + kt * 64;
  };

  short8 rab[4];
  float4 raf[8];
  float4 rb[8];
  if constexpr (ABF16) load_tile_bf(Abf(0), FD, rab); else load_tile(Af(0), FD, raf);
  load_tile(Bb(0), FD, rb);

  for (int it = 0; it < nit; ++it) {
    if constexpr (ABF16) write_tile_bf(sA, rab); else write_tile(sA, raf);
    write_tile(sB, rb);
    __syncthreads();
    if (it + 1 < nit) {
      if constexpr (ABF16) load_tile_bf(Abf(it + 1), FD, rab);
      else                 load_tile(Af(it + 1), FD, raf);
      load_tile(Bb(it + 1), FD, rb);
    }
    compute_tile(sA, sB, acc, wr, wc, l16, h16);
    __syncthreads();
  }

#pragma unroll
  for (int j = 0; j < 4; ++j) {
    int col = h0 + wc * 64 + j * 16 + l16;
    float bsum = 0.f;
    for (int l = 0; l <= lp; ++l) {
      int p = l * LL - l * (l - 1) / 2 + (lp - l);
      bsum += bd[(size_t)p * HD + col];
    }
#pragma unroll
    for (int i = 0; i < 4; ++i) {
      int rbase = m0 + wr * 64 + i * 16 + h16 * 4;
#pragma unroll
      for (int q = 0; q < 4; ++q) {
        recon[((size_t)lp * MT + rbase + q) * HD + col] = acc[i][j][q] + bsum;
      }
    }
  }
}

extern "C" void kernel_launch(void* const* d_in, const int* in_sizes, int n_in,
                              void* d_out, int out_size, void* d_ws, size_t ws_size,
                              hipStream_t stream) {
  const float* res    = (const float*)d_in[0];
  const float* We     = (const float*)d_in[1];
  const float* be     = (const float*)d_in[2];
  const float* Wd     = (const float*)d_in[3];
  const float* bd     = (const float*)d_in[4];
  const float* thresh = (const float*)d_in[5];

  float* recon = (float*)d_out;                       // L*M*H
  float* feats = recon + (size_t)LL * MT * HD;        // L*M*F

  const size_t featsbf_bytes = (size_t)LL * MT * FD * sizeof(unsigned short); // 128 MiB
  const size_t wdbf_bytes    = (size_t)36 * HD * FD * sizeof(unsigned short); // 288 MiB
  const bool use_bf   = ws_size >= featsbf_bytes;
  const bool use_full = ws_size >= featsbf_bytes + wdbf_bytes;

  unsigned short* feats_bf = use_bf ? (unsigned short*)d_ws : nullptr;
  unsigned short* wd_bf    = (unsigned short*)((char*)d_ws + featsbf_bytes);

  if (use_full) {
    enc_kernel<<<dim3(FD / 128, MT / 128, LL), dim3(256), 0, stream>>>(
        res, We, be, thresh, feats, feats_bf, Wd, wd_bf);
    dec8<<<dim3(HD / 128, MT / 256, 4), dim3(512), 0, stream>>>(
        feats_bf, wd_bf, bd, recon);
  } else {
    enc_kernel<<<dim3(FD / 128, MT / 128, LL), dim3(256), 0, stream>>>(
        res, We, be, thresh, feats, feats_bf, nullptr, nullptr);
    if (use_bf)
      dec_kernel<true><<<dim3(HD / 128, MT / 128, LL), dim3(256), 0, stream>>>(
          feats, feats_bf, Wd, bd, recon);
    else
      dec_kernel<false><<<dim3(HD / 128, MT / 128, LL), dim3(256), 0, stream>>>(
          feats, nullptr, Wd, bd, recon);
  }
}